// Round 14
// baseline (307.913 us; speedup 1.0000x reference)
//
#include <hip/hip_runtime.h>
#include <math.h>

#define EMB 1024
#define NB 4
#define SQ 2048
#define TOK (NB*SQ)   // 8192

typedef __attribute__((ext_vector_type(8))) short bhalf8;   // 8 bf16 (4 VGPRs)
typedef __attribute__((ext_vector_type(4))) float f32x4;

__device__ __forceinline__ unsigned short f32_to_bf16(float f) {
    unsigned int u = __float_as_uint(f);
    u += 0x7FFFu + ((u >> 16) & 1u);       // round-to-nearest-even
    return (unsigned short)(u >> 16);
}
__device__ __forceinline__ float bf16_to_f32(unsigned short h) {
    return __uint_as_float(((unsigned int)h) << 16);
}

// ---------------- fused fp32 -> bf16 conversion + Sf zeroing ----------------
__global__ __launch_bounds__(256) void convert_all_kernel(
    const float* __restrict__ x,  unsigned short* __restrict__ x_bf,
    const float* __restrict__ rot, const float* __restrict__ ent,
    const float* __restrict__ gw, unsigned short* __restrict__ w_bf,
    float* __restrict__ Sf) {
    const int EE4 = EMB * EMB / 4;
    const int XB = TOK*EMB/4/256;      // 8192 blocks for x
    const int WB = 5*EE4/256;          // 5120 blocks for weights
    const float* src;
    unsigned short* dst;
    float scale = 1.0f;
    int j;
    if (blockIdx.x < XB) {
        src = x; dst = x_bf; j = blockIdx.x * 256 + threadIdx.x;
        float4 v = ((const float4*)src)[j];
        ushort4 o = { f32_to_bf16(v.x), f32_to_bf16(v.y), f32_to_bf16(v.z), f32_to_bf16(v.w) };
        ((ushort4*)dst)[j] = o;
        return;
    }
    if (blockIdx.x >= XB + WB) {       // zero Sf (NB*SQ floats = 2048 float4)
        const int z = (blockIdx.x - XB - WB) * 256 + threadIdx.x;
        float4 zz = {0.f, 0.f, 0.f, 0.f};
        ((float4*)Sf)[z] = zz;
        return;
    }
    const int i = (blockIdx.x - XB) * 256 + threadIdx.x;   // over 5*EE4
    j = i; dst = w_bf;
    if (i < 3 * EE4) {
        src = rot;
        if (i < EE4) scale = 0.125f;                // 1/sqrt(64) folded into q-rows
    } else if (i < 4 * EE4) { src = ent; j = i - 3 * EE4; }
    else                    { src = gw;  j = i - 4 * EE4; }
    float4 v = ((const float4*)src)[j];
    ushort4 o;
    o.x = f32_to_bf16(v.x * scale);
    o.y = f32_to_bf16(v.y * scale);
    o.z = f32_to_bf16(v.z * scale);
    o.w = f32_to_bf16(v.w * scale);
    ((ushort4*)dst)[i] = o;
}

// ---------------- async global->LDS 16B staging helper ----------------
__device__ __forceinline__ void async_load16(const unsigned short* gp, unsigned short* lp) {
    __builtin_amdgcn_global_load_lds(
        (const __attribute__((address_space(1))) unsigned int*)gp,
        (__attribute__((address_space(3))) unsigned int*)lp,
        16, 0, 0);
}

// =====================================================================================
// 128xTN NT GEMM (m97 structure), NW waves (NW*64 threads).
// R12 insight: occupancy class is set by VGPR+AGPR sum. acc[4][4] (64 AGPR) + 80 VGPR
// = 144 effective -> only 8 waves/CU. Halving per-wave acc to [4][2] (NW=8 at TN=128,
// or TN=64 at NW=4) lands in the (64,128] class -> 16 waves/CU.
//   TN=128, NW=8: 8 waves of 64x32, 512 thr, 32 KB LDS   (K1, K2)
//   TN=64,  NW=4: 4 waves of 64x32, 256 thr, 24 KB LDS   (K4, K5, K6 - R11 config)
// C[m,n] = sum_k A[m,k]*B[n,k], bf16 in, fp32 acc. Zero bank conflicts (verified).
// Epilogue MODEs:
//   0: C bf16 <- v                                  (K5)
//   1: C bf16 <- exp(v-16); row-sums atomicAdd->Sf  (K2: unnormalized softmax P)
//   2: Fout f32 <- sigmoid(v) * bf16(Obf[idx])      (K6: final gate)
//   3: C bf16 <- v / Sf[row]                        (K4: normalize attn output)
//   5: bn<2048: C bf16 <- v (q,k);  bn>=2048: transposed ushort4 write to Vt (v)
// =====================================================================================
template <int MODE, int TN, int NW>
__global__ __launch_bounds__(NW*64) void gemm_nt_128(
    const unsigned short* __restrict__ A,
    const unsigned short* __restrict__ B,
    void* __restrict__ C,
    const unsigned short* __restrict__ Obf,
    float* __restrict__ Fout,
    float* __restrict__ Sf,
    unsigned short* __restrict__ Vt,
    int M, int N, int K, int lda, int ldb, int ldc,
    long sA, long sB, long sC)
{
    constexpr int NWN = NW / 2;        // waves along N (2 or 4)
    constexpr int WN  = TN / NWN;      // wave N-tile (32 both configs)
    constexpr int NI  = WN / 16;       // B-frags per wave (2)
    __shared__ __align__(16) unsigned short As[128*64];   // 16 KB
    __shared__ __align__(16) unsigned short Bs[TN*64];    // 16 or 8 KB

    const int bz = blockIdx.z;
    const unsigned short* Ab = A + (long)bz * sA;
    const unsigned short* Bb = B + (long)bz * sB;
    const int bm = blockIdx.x * 128;
    const int bn = blockIdx.y * TN;
    const int t = threadIdx.x;
    const int w = t >> 6;        // wave 0..NW-1
    const int l = t & 63;        // lane
    const int srow8 = l >> 3;
    const int scol  = (((l & 7) ^ ((l >> 3) & 7)) * 8);

    f32x4 zero = {0.f, 0.f, 0.f, 0.f};
    f32x4 acc[4][NI];
    #pragma unroll
    for (int i = 0; i < 4; ++i)
        #pragma unroll
        for (int j = 0; j < NI; ++j) acc[i][j] = zero;

    const int wm = (w / NWN) * 64;
    const int wn = (w % NWN) * WN;
    const int fr = l & 15;
    const int kqs0 = ((((l >> 4)    ) ^ (l & 7)) * 8);
    const int kqs1 = (((4 + (l >> 4)) ^ (l & 7)) * 8);

    const int nkt = K >> 6;
    for (int kt = 0; kt < nkt; ++kt) {
        const int k0 = kt << 6;
        __syncthreads();
        #pragma unroll
        for (int r = 0; r < 16/NW; ++r) {
            const int rb = r*NW + w;                 // row-block 0..15 (8 rows each)
            const int rr = rb * 8 + srow8;
            async_load16(Ab + (long)(bm + rr) * lda + (k0 + scol), As + rb * 512);
            if (TN == 128 || rb < TN/8)
                async_load16(Bb + (long)(bn + rr) * ldb + (k0 + scol), Bs + rb * 512);
        }
        __syncthreads();

        #pragma unroll
        for (int h = 0; h < 2; ++h) {
            const int kq = h ? kqs1 : kqs0;
            bhalf8 af[4], bfr[NI];
            #pragma unroll
            for (int mi = 0; mi < 4; ++mi)
                af[mi] = *(const bhalf8*)(As + (wm + mi*16 + fr) * 64 + kq);
            #pragma unroll
            for (int ni = 0; ni < NI; ++ni)
                bfr[ni] = *(const bhalf8*)(Bs + (wn + ni*16 + fr) * 64 + kq);
            #pragma unroll
            for (int mi = 0; mi < 4; ++mi)
                #pragma unroll
                for (int ni = 0; ni < NI; ++ni)
                    acc[mi][ni] = __builtin_amdgcn_mfma_f32_16x16x32_bf16(
                        af[mi], bfr[ni], acc[mi][ni], 0, 0, 0);
        }
    }

    // C/D layout (m89-verified): col = lane&15, row = (lane>>4)*4 + reg
    const int crow = (l >> 4) * 4;
    const int ccol = l & 15;

    float psum[4][4];                 // MODE 1: per-(mi,r) partial row sums
    if (MODE == 1) {
        #pragma unroll
        for (int mi = 0; mi < 4; ++mi)
            #pragma unroll
            for (int r = 0; r < 4; ++r) psum[mi][r] = 0.f;
    }
    float rinv[4][4];                 // MODE 3: per-(mi,r) 1/rowsum
    if (MODE == 3) {
        #pragma unroll
        for (int mi = 0; mi < 4; ++mi)
            #pragma unroll
            for (int r = 0; r < 4; ++r)
                rinv[mi][r] = 1.0f / Sf[(long)bz * SQ + bm + wm + mi*16 + crow + r];
    }

    const bool vtile = (MODE == 5) && (bn >= 2*EMB);   // block-uniform

    #pragma unroll
    for (int mi = 0; mi < 4; ++mi) {
        #pragma unroll
        for (int ni = 0; ni < NI; ++ni) {
            if (MODE == 5 && vtile) {
                // transposed v write: vT[b][e][s], e = gc-2048, s = token row in batch
                const int gc = bn + wn + ni*16 + ccol;        // 2048..3071
                const int e  = gc - 2*EMB;
                const int b  = bm >> 11;                      // SQ = 2048
                const int s0 = (bm & (SQ-1)) + wm + mi*16 + crow;
                ushort4 o;
                o.x = f32_to_bf16(acc[mi][ni][0]);
                o.y = f32_to_bf16(acc[mi][ni][1]);
                o.z = f32_to_bf16(acc[mi][ni][2]);
                o.w = f32_to_bf16(acc[mi][ni][3]);
                *(ushort4*)(Vt + ((long)(b*EMB + e)) * SQ + s0) = o;
                continue;
            }
            #pragma unroll
            for (int r = 0; r < 4; ++r) {
                const int gr = bm + wm + mi*16 + crow + r;
                const int gc = bn + wn + ni*16 + ccol;
                const float v = acc[mi][ni][r];
                const long idx = (long)gr * ldc + gc;
                if (MODE == 0 || MODE == 5) {
                    ((unsigned short*)C)[(long)bz*sC + idx] = f32_to_bf16(v);
                } else if (MODE == 1) {
                    const unsigned short p = f32_to_bf16(__expf(v - 16.0f));
                    ((unsigned short*)C)[(long)bz*sC + idx] = p;
                    psum[mi][r] += bf16_to_f32(p);   // sum the ROUNDED value (matches K4 read)
                } else if (MODE == 3) {
                    ((unsigned short*)C)[(long)bz*sC + idx] = f32_to_bf16(v * rinv[mi][r]);
                } else {   // MODE 2
                    const float o = bf16_to_f32(Obf[idx]);
                    const float g = 1.0f / (1.0f + __expf(-v));
                    Fout[idx] = g * o;
                }
            }
        }
    }

    if (MODE == 1) {
        // reduce across the 16 ccol lanes of each crow group, 1 atomic per group
        #pragma unroll
        for (int mi = 0; mi < 4; ++mi) {
            #pragma unroll
            for (int r = 0; r < 4; ++r) {
                float s_ = psum[mi][r];
                s_ += __shfl_xor(s_, 1);
                s_ += __shfl_xor(s_, 2);
                s_ += __shfl_xor(s_, 4);
                s_ += __shfl_xor(s_, 8);
                if ((l & 15) == 0)
                    atomicAdd(&Sf[(long)bz * SQ + bm + wm + mi*16 + crow + r], s_);
            }
        }
    }
}

extern "C" void kernel_launch(void* const* d_in, const int* in_sizes, int n_in,
                              void* d_out, int out_size, void* d_ws, size_t ws_size,
                              hipStream_t stream) {
    const float* rot = (const float*)d_in[0];   // (3E, E) row-major
    const float* ent = (const float*)d_in[1];   // (E, E)
    const float* x   = (const float*)d_in[2];   // (B, S, E)
    const float* gw  = (const float*)d_in[3];   // (E, E)
    float* outp = (float*)d_out;
    char* ws = (char*)d_ws;

    size_t off = 0;
    unsigned short* x_bf    = (unsigned short*)(ws + off); off += (size_t)TOK*EMB*2;     // 16 MB
    unsigned short* wqkv_bf = (unsigned short*)(ws + off); off += (size_t)3*EMB*EMB*2;   // 6 MB
    unsigned short* wout_bf = (unsigned short*)(ws + off); off += (size_t)EMB*EMB*2;     // 2 MB
    unsigned short* gate_bf = (unsigned short*)(ws + off); off += (size_t)EMB*EMB*2;     // 2 MB
    unsigned short* qkv_bf  = (unsigned short*)(ws + off); off += (size_t)TOK*3*EMB*2;   // 48 MB
    unsigned short* vT_bf   = (unsigned short*)(ws + off); off += (size_t)NB*EMB*SQ*2;   // 16 MB
    unsigned short* p_bf    = (unsigned short*)(ws + off); off += (size_t)NB*SQ*SQ*2;    // 32 MB (P)
    float*          sf      = (float*)(ws + off);          off += (size_t)NB*SQ*4;       // 32 KB
    // Aliases (lifetimes disjoint, all launches sequential on one stream):
    unsigned short* ao_bf   = x_bf;                          // x dead after K1; ao live K4->K5
    unsigned short* out_bf  = qkv_bf + (size_t)NB*SQ*SQ;     // qkv dead after K2; out live K5->K6

    // K0: all converts + Sf zeroing in one launch
    convert_all_kernel<<<dim3(TOK*EMB/4/256 + 5*EMB*EMB/4/256 + NB*SQ/4/256), dim3(256),
                         0, stream>>>(x, x_bf, rot, ent, gw, wqkv_bf, sf);

    // K1: qkv = x @ w_qkv^T (8192 x 3072, K=1024); q,k -> qkv_bf, v -> vT_bf transposed
    //     [1536 blocks, TN=128, 8 waves]
    gemm_nt_128<5,128,8><<<dim3(TOK/128, 3*EMB/128, 1), dim3(512), 0, stream>>>(
        x_bf, wqkv_bf, qkv_bf, nullptr, nullptr, nullptr, vT_bf,
        TOK, 3*EMB, EMB, EMB, EMB, 3*EMB, 0, 0, 0);

    // K2: P = exp(q @ k^T - 16) per batch (2048 x 2048, K=1024) -> bf16 P + row sums
    //     [1024 blocks, TN=128, 8 waves]
    gemm_nt_128<1,128,8><<<dim3(SQ/128, SQ/128, NB), dim3(512), 0, stream>>>(
        qkv_bf, qkv_bf + EMB, p_bf, nullptr, nullptr, sf, nullptr,
        SQ, SQ, EMB, 3*EMB, 3*EMB, SQ,
        (long)SQ*3*EMB, (long)SQ*3*EMB, (long)SQ*SQ);

    // K4: attn_out = (P @ v) / rowsum per batch (2048 x 1024, K=2048); B = vT (NT form)
    //     [1024 blocks, TN=64, 4 waves]
    gemm_nt_128<3,64,4><<<dim3(SQ/128, EMB/64, NB), dim3(256), 0, stream>>>(
        p_bf, vT_bf, ao_bf, nullptr, nullptr, sf, nullptr,
        SQ, EMB, SQ, SQ, SQ, EMB,
        (long)SQ*SQ, (long)EMB*SQ, (long)SQ*EMB);

    // K5: out = attn_out @ w_out^T (8192 x 1024, K=1024) -> bf16  [1024 blocks, TN=64]
    gemm_nt_128<0,64,4><<<dim3(TOK/128, EMB/64, 1), dim3(256), 0, stream>>>(
        ao_bf, wout_bf, out_bf, nullptr, nullptr, nullptr, nullptr,
        TOK, EMB, EMB, EMB, EMB, EMB, 0, 0, 0);

    // K6: result = sigmoid(out @ gate_w^T) * out_bf -> fp32 d_out  [1024 blocks, TN=64]
    gemm_nt_128<2,64,4><<<dim3(TOK/128, EMB/64, 1), dim3(256), 0, stream>>>(
        out_bf, gate_bf, nullptr, out_bf, outp, nullptr, nullptr,
        TOK, EMB, EMB, EMB, EMB, EMB, 0, 0, 0);
}

// Round 15
// 295.561 us; speedup vs baseline: 1.0418x; 1.0418x over previous
//
#include <hip/hip_runtime.h>
#include <math.h>

#define EMB 1024
#define NB 4
#define SQ 2048
#define TOK (NB*SQ)   // 8192

typedef __attribute__((ext_vector_type(8))) short bhalf8;   // 8 bf16 (4 VGPRs)
typedef __attribute__((ext_vector_type(4))) float f32x4;

__device__ __forceinline__ unsigned short f32_to_bf16(float f) {
    unsigned int u = __float_as_uint(f);
    u += 0x7FFFu + ((u >> 16) & 1u);       // round-to-nearest-even
    return (unsigned short)(u >> 16);
}
__device__ __forceinline__ float bf16_to_f32(unsigned short h) {
    return __uint_as_float(((unsigned int)h) << 16);
}

// ---------------- fused fp32 -> bf16 conversion + Sf zeroing ----------------
__global__ __launch_bounds__(256) void convert_all_kernel(
    const float* __restrict__ x,  unsigned short* __restrict__ x_bf,
    const float* __restrict__ rot, const float* __restrict__ ent,
    const float* __restrict__ gw, unsigned short* __restrict__ w_bf,
    float* __restrict__ Sf) {
    const int EE4 = EMB * EMB / 4;
    const int XB = TOK*EMB/4/256;      // 8192 blocks for x
    const int WB = 5*EE4/256;          // 5120 blocks for weights
    const float* src;
    unsigned short* dst;
    float scale = 1.0f;
    int j;
    if (blockIdx.x < XB) {
        src = x; dst = x_bf; j = blockIdx.x * 256 + threadIdx.x;
        float4 v = ((const float4*)src)[j];
        ushort4 o = { f32_to_bf16(v.x), f32_to_bf16(v.y), f32_to_bf16(v.z), f32_to_bf16(v.w) };
        ((ushort4*)dst)[j] = o;
        return;
    }
    if (blockIdx.x >= XB + WB) {       // zero Sf (NB*SQ floats = 2048 float4)
        const int z = (blockIdx.x - XB - WB) * 256 + threadIdx.x;
        float4 zz = {0.f, 0.f, 0.f, 0.f};
        ((float4*)Sf)[z] = zz;
        return;
    }
    const int i = (blockIdx.x - XB) * 256 + threadIdx.x;   // over 5*EE4
    j = i; dst = w_bf;
    if (i < 3 * EE4) {
        src = rot;
        if (i < EE4) scale = 0.125f;                // 1/sqrt(64) folded into q-rows
    } else if (i < 4 * EE4) { src = ent; j = i - 3 * EE4; }
    else                    { src = gw;  j = i - 4 * EE4; }
    float4 v = ((const float4*)src)[j];
    ushort4 o;
    o.x = f32_to_bf16(v.x * scale);
    o.y = f32_to_bf16(v.y * scale);
    o.z = f32_to_bf16(v.z * scale);
    o.w = f32_to_bf16(v.w * scale);
    ((ushort4*)dst)[i] = o;
}

// ---------------- async global->LDS 16B staging helper ----------------
__device__ __forceinline__ void async_load16(const unsigned short* gp, unsigned short* lp) {
    __builtin_amdgcn_global_load_lds(
        (const __attribute__((address_space(1))) unsigned int*)gp,
        (__attribute__((address_space(3))) unsigned int*)lp,
        16, 0, 0);
}

// =====================================================================================
// 128xTN NT GEMM (m97 structure), NW waves. R15 = R11 config (best 300.8us) + K1
// splitting q,k into SEPARATE DENSE buffers (ld=1024) so K2's panels are stride-1024
// dense instead of stride-3072 interleaved (K2 was 510 TF vs K1's 763 at identical
// tile/occupancy; panel page density is the tested difference).
//   TN=128, NW=4: 4 waves of 64x64 (acc 4x4), 32 KB LDS  (K1, K2)
//   TN=64,  NW=4: 4 waves of 64x32 (acc 4x2), 24 KB LDS  (K4, K5, K6)
// Epilogue MODEs:
//   0: C bf16 <- v                                  (K5)
//   1: C bf16 <- exp(v-16); row-sums atomicAdd->Sf  (K2)
//   2: Fout f32 <- sigmoid(v) * bf16(Obf[idx])      (K6)
//   3: C bf16 <- v / Sf[row]                        (K4)
//   5: bn<E: q->C (ld E); E<=bn<2E: k->Fout-as-ushort (ld E); bn>=2E: vT transposed
// =====================================================================================
template <int MODE, int TN, int NW>
__global__ __launch_bounds__(NW*64) void gemm_nt_128(
    const unsigned short* __restrict__ A,
    const unsigned short* __restrict__ B,
    void* __restrict__ C,
    const unsigned short* __restrict__ Obf,
    float* __restrict__ Fout,
    float* __restrict__ Sf,
    unsigned short* __restrict__ Vt,
    int M, int N, int K, int lda, int ldb, int ldc,
    long sA, long sB, long sC)
{
    constexpr int NWN = NW / 2;
    constexpr int WN  = TN / NWN;
    constexpr int NI  = WN / 16;
    __shared__ __align__(16) unsigned short As[128*64];
    __shared__ __align__(16) unsigned short Bs[TN*64];

    const int bz = blockIdx.z;
    const unsigned short* Ab = A + (long)bz * sA;
    const unsigned short* Bb = B + (long)bz * sB;
    const int bm = blockIdx.x * 128;
    const int bn = blockIdx.y * TN;
    const int t = threadIdx.x;
    const int w = t >> 6;
    const int l = t & 63;
    const int srow8 = l >> 3;
    const int scol  = (((l & 7) ^ ((l >> 3) & 7)) * 8);

    f32x4 zero = {0.f, 0.f, 0.f, 0.f};
    f32x4 acc[4][NI];
    #pragma unroll
    for (int i = 0; i < 4; ++i)
        #pragma unroll
        for (int j = 0; j < NI; ++j) acc[i][j] = zero;

    const int wm = (w / NWN) * 64;
    const int wn = (w % NWN) * WN;
    const int fr = l & 15;
    const int kqs0 = ((((l >> 4)    ) ^ (l & 7)) * 8);
    const int kqs1 = (((4 + (l >> 4)) ^ (l & 7)) * 8);

    const int nkt = K >> 6;
    for (int kt = 0; kt < nkt; ++kt) {
        const int k0 = kt << 6;
        __syncthreads();
        #pragma unroll
        for (int r = 0; r < 16/NW; ++r) {
            const int rb = r*NW + w;
            const int rr = rb * 8 + srow8;
            async_load16(Ab + (long)(bm + rr) * lda + (k0 + scol), As + rb * 512);
            if (TN == 128 || rb < TN/8)
                async_load16(Bb + (long)(bn + rr) * ldb + (k0 + scol), Bs + rb * 512);
        }
        __syncthreads();

        #pragma unroll
        for (int h = 0; h < 2; ++h) {
            const int kq = h ? kqs1 : kqs0;
            bhalf8 af[4], bfr[NI];
            #pragma unroll
            for (int mi = 0; mi < 4; ++mi)
                af[mi] = *(const bhalf8*)(As + (wm + mi*16 + fr) * 64 + kq);
            #pragma unroll
            for (int ni = 0; ni < NI; ++ni)
                bfr[ni] = *(const bhalf8*)(Bs + (wn + ni*16 + fr) * 64 + kq);
            #pragma unroll
            for (int mi = 0; mi < 4; ++mi)
                #pragma unroll
                for (int ni = 0; ni < NI; ++ni)
                    acc[mi][ni] = __builtin_amdgcn_mfma_f32_16x16x32_bf16(
                        af[mi], bfr[ni], acc[mi][ni], 0, 0, 0);
        }
    }

    // C/D layout (m89-verified): col = lane&15, row = (lane>>4)*4 + reg
    const int crow = (l >> 4) * 4;
    const int ccol = l & 15;

    float psum[4][4];
    if (MODE == 1) {
        #pragma unroll
        for (int mi = 0; mi < 4; ++mi)
            #pragma unroll
            for (int r = 0; r < 4; ++r) psum[mi][r] = 0.f;
    }
    float rinv[4][4];
    if (MODE == 3) {
        #pragma unroll
        for (int mi = 0; mi < 4; ++mi)
            #pragma unroll
            for (int r = 0; r < 4; ++r)
                rinv[mi][r] = 1.0f / Sf[(long)bz * SQ + bm + wm + mi*16 + crow + r];
    }

    // MODE 5 routing (block-uniform): 0 = q, 1 = k, 2 = v-transposed
    const int vsel = (MODE == 5) ? ((bn >= 2*EMB) ? 2 : (bn >= EMB ? 1 : 0)) : 0;
    unsigned short* qk_dst = (MODE == 5)
        ? (vsel == 0 ? (unsigned short*)C : (unsigned short*)Fout) : nullptr;
    const int qk_sub = (MODE == 5 && vsel == 1) ? EMB : 0;

    #pragma unroll
    for (int mi = 0; mi < 4; ++mi) {
        #pragma unroll
        for (int ni = 0; ni < NI; ++ni) {
            if (MODE == 5 && vsel == 2) {
                const int gc = bn + wn + ni*16 + ccol;        // 2048..3071
                const int e  = gc - 2*EMB;
                const int b  = bm >> 11;                      // SQ = 2048
                const int s0 = (bm & (SQ-1)) + wm + mi*16 + crow;
                ushort4 o;
                o.x = f32_to_bf16(acc[mi][ni][0]);
                o.y = f32_to_bf16(acc[mi][ni][1]);
                o.z = f32_to_bf16(acc[mi][ni][2]);
                o.w = f32_to_bf16(acc[mi][ni][3]);
                *(ushort4*)(Vt + ((long)(b*EMB + e)) * SQ + s0) = o;
                continue;
            }
            #pragma unroll
            for (int r = 0; r < 4; ++r) {
                const int gr = bm + wm + mi*16 + crow + r;
                const int gc = bn + wn + ni*16 + ccol;
                const float v = acc[mi][ni][r];
                if (MODE == 5) {
                    qk_dst[(long)gr * EMB + (gc - qk_sub)] = f32_to_bf16(v);
                    continue;
                }
                const long idx = (long)gr * ldc + gc;
                if (MODE == 0) {
                    ((unsigned short*)C)[(long)bz*sC + idx] = f32_to_bf16(v);
                } else if (MODE == 1) {
                    const unsigned short p = f32_to_bf16(__expf(v - 16.0f));
                    ((unsigned short*)C)[(long)bz*sC + idx] = p;
                    psum[mi][r] += bf16_to_f32(p);
                } else if (MODE == 3) {
                    ((unsigned short*)C)[(long)bz*sC + idx] = f32_to_bf16(v * rinv[mi][r]);
                } else {   // MODE 2
                    const float o = bf16_to_f32(Obf[idx]);
                    const float g = 1.0f / (1.0f + __expf(-v));
                    Fout[idx] = g * o;
                }
            }
        }
    }

    if (MODE == 1) {
        #pragma unroll
        for (int mi = 0; mi < 4; ++mi) {
            #pragma unroll
            for (int r = 0; r < 4; ++r) {
                float s_ = psum[mi][r];
                s_ += __shfl_xor(s_, 1);
                s_ += __shfl_xor(s_, 2);
                s_ += __shfl_xor(s_, 4);
                s_ += __shfl_xor(s_, 8);
                if ((l & 15) == 0)
                    atomicAdd(&Sf[(long)bz * SQ + bm + wm + mi*16 + crow + r], s_);
            }
        }
    }
}

extern "C" void kernel_launch(void* const* d_in, const int* in_sizes, int n_in,
                              void* d_out, int out_size, void* d_ws, size_t ws_size,
                              hipStream_t stream) {
    const float* rot = (const float*)d_in[0];   // (3E, E) row-major
    const float* ent = (const float*)d_in[1];   // (E, E)
    const float* x   = (const float*)d_in[2];   // (B, S, E)
    const float* gw  = (const float*)d_in[3];   // (E, E)
    float* outp = (float*)d_out;
    char* ws = (char*)d_ws;

    size_t off = 0;
    unsigned short* x_bf    = (unsigned short*)(ws + off); off += (size_t)TOK*EMB*2;     // 16 MB
    unsigned short* wqkv_bf = (unsigned short*)(ws + off); off += (size_t)3*EMB*EMB*2;   // 6 MB
    unsigned short* wout_bf = (unsigned short*)(ws + off); off += (size_t)EMB*EMB*2;     // 2 MB
    unsigned short* gate_bf = (unsigned short*)(ws + off); off += (size_t)EMB*EMB*2;     // 2 MB
    unsigned short* q_bf    = (unsigned short*)(ws + off); off += (size_t)TOK*EMB*2;     // 16 MB (ld=E)
    unsigned short* k_bf    = (unsigned short*)(ws + off); off += (size_t)TOK*EMB*2;     // 16 MB (ld=E)
    unsigned short* vT_bf   = (unsigned short*)(ws + off); off += (size_t)NB*EMB*SQ*2;   // 16 MB
    unsigned short* p_bf    = (unsigned short*)(ws + off); off += (size_t)NB*SQ*SQ*2;    // 32 MB
    float*          sf      = (float*)(ws + off);          off += (size_t)NB*SQ*4;       // 32 KB
    // Aliases (lifetimes disjoint):
    unsigned short* ao_bf   = x_bf;    // x dead after K1; ao live K4->K5
    unsigned short* out_bf  = q_bf;    // q dead after K2; out live K5->K6

    // K0: all converts + Sf zeroing
    convert_all_kernel<<<dim3(TOK*EMB/4/256 + 5*EMB*EMB/4/256 + NB*SQ/4/256), dim3(256),
                         0, stream>>>(x, x_bf, rot, ent, gw, wqkv_bf, sf);

    // K1: qkv projection; q -> q_bf (ld E), k -> k_bf (ld E), v -> vT transposed
    gemm_nt_128<5,128,4><<<dim3(TOK/128, 3*EMB/128, 1), dim3(256), 0, stream>>>(
        x_bf, wqkv_bf, q_bf, nullptr, (float*)k_bf, nullptr, vT_bf,
        TOK, 3*EMB, EMB, EMB, EMB, EMB, 0, 0, 0);

    // K2: P = exp(q @ k^T - 16) per batch -> bf16 P + row sums (dense ld=1024 panels)
    gemm_nt_128<1,128,4><<<dim3(SQ/128, SQ/128, NB), dim3(256), 0, stream>>>(
        q_bf, k_bf, p_bf, nullptr, nullptr, sf, nullptr,
        SQ, SQ, EMB, EMB, EMB, SQ,
        (long)SQ*EMB, (long)SQ*EMB, (long)SQ*SQ);

    // K4: attn_out = (P @ v) / rowsum per batch; B = vT (NT form)
    gemm_nt_128<3,64,4><<<dim3(SQ/128, EMB/64, NB), dim3(256), 0, stream>>>(
        p_bf, vT_bf, ao_bf, nullptr, nullptr, sf, nullptr,
        SQ, EMB, SQ, SQ, SQ, EMB,
        (long)SQ*SQ, (long)EMB*SQ, (long)SQ*EMB);

    // K5: out = attn_out @ w_out^T -> bf16
    gemm_nt_128<0,64,4><<<dim3(TOK/128, EMB/64, 1), dim3(256), 0, stream>>>(
        ao_bf, wout_bf, out_bf, nullptr, nullptr, nullptr, nullptr,
        TOK, EMB, EMB, EMB, EMB, EMB, 0, 0, 0);

    // K6: result = sigmoid(out @ gate_w^T) * out_bf -> fp32 d_out
    gemm_nt_128<2,64,4><<<dim3(TOK/128, EMB/64, 1), dim3(256), 0, stream>>>(
        out_bf, gate_bf, nullptr, out_bf, outp, nullptr, nullptr,
        TOK, EMB, EMB, EMB, EMB, EMB, 0, 0, 0);
}